// Round 8
// baseline (344.331 us; speedup 1.0000x reference)
//
#include <hip/hip_runtime.h>
#include <cstdint>
#include <cstddef>

#define EDIM 256
#define VDIM 8192
#define NPIX 16384

typedef __attribute__((ext_vector_type(8))) short          bf16x8;
typedef __attribute__((ext_vector_type(8))) unsigned short u16x8;
typedef __attribute__((ext_vector_type(4))) float          f32x4;
typedef __attribute__((ext_vector_type(2))) float          f32x2;

// RNE float->bf16
__device__ __forceinline__ unsigned short f2bf(float x) {
    unsigned int u = __float_as_uint(x);
    return (unsigned short)((u + 0x7fffu + ((u >> 16) & 1u)) >> 16);
}

__device__ __forceinline__ void gload_lds16(const void* gsrc, void* ldst) {
#if defined(__has_builtin) && __has_builtin(__builtin_amdgcn_global_load_lds)
    __builtin_amdgcn_global_load_lds(
        (const __attribute__((address_space(1))) unsigned int*)gsrc,
        (__attribute__((address_space(3))) unsigned int*)ldst, 16, 0, 0);
#else
    *(float4*)ldst = *(const float4*)gsrc;
#endif
}

// ---------- numpy pairwise sum-of-squares (exact semantics, verified r2) ----------
__device__ __forceinline__ float np_sqpair128(const float* __restrict__ z) {
    float r[8];
#pragma unroll
    for (int j = 0; j < 8; ++j) r[j] = __fmul_rn(z[j], z[j]);
    for (int i = 8; i < 128; i += 8) {
#pragma unroll
        for (int j = 0; j < 8; ++j)
            r[j] = __fadd_rn(r[j], __fmul_rn(z[i + j], z[i + j]));
    }
    float t01 = __fadd_rn(r[0], r[1]), t23 = __fadd_rn(r[2], r[3]);
    float t45 = __fadd_rn(r[4], r[5]), t67 = __fadd_rn(r[6], r[7]);
    return __fadd_rn(__fadd_rn(t01, t23), __fadd_rn(t45, t67));
}

// ---------------- Stage 1 (FUSED): z32 + zbf frags + A32 + thr ----------------
__global__ __launch_bounds__(256) void pre_quant_fused(const float* __restrict__ x,
                                                       const float* __restrict__ Wpre,
                                                       const float* __restrict__ bpre,
                                                       float* __restrict__ z32,
                                                       unsigned short* __restrict__ zbf,
                                                       float* __restrict__ A32,
                                                       float* __restrict__ thr) {
#pragma clang fp contract(off)
    __shared__ float xs[32][36];
    __shared__ float wt[32][260];   // [c][e]; aliased as zs[32][260] in epilogue
    int n0 = blockIdx.x * 32;
    int b = n0 >> 8, pix0 = n0 & 255;
    int t = threadIdx.x;
    int ep = t & 31, pg = t >> 5;

    f32x2 acc[4][4];
#pragma unroll
    for (int pi = 0; pi < 4; ++pi)
#pragma unroll
        for (int j = 0; j < 4; ++j) acc[pi][j] = (f32x2){0.f, 0.f};

    for (int c0 = 0; c0 < 256; c0 += 32) {
        __syncthreads();
        {   int cc = t >> 3, pp = (t & 7) * 4;
            *(float4*)&xs[cc][pp] =
                *(const float4*)&x[(size_t)b * 65536 + (size_t)(c0 + cc) * 256 + pix0 + pp];
        }
        {   const float* wr = Wpre + (size_t)t * 256 + c0;
#pragma unroll
            for (int i = 0; i < 32; i += 4) {
                float4 v = *(const float4*)&wr[i];
                wt[i + 0][t] = v.x; wt[i + 1][t] = v.y;
                wt[i + 2][t] = v.z; wt[i + 3][t] = v.w;
            }
        }
        __syncthreads();
#pragma unroll 8
        for (int cc = 0; cc < 32; ++cc) {
            float4 xv = *(const float4*)&xs[cc][pg * 4];
            float xa[4] = {xv.x, xv.y, xv.z, xv.w};
            f32x2 wv[4];
#pragma unroll
            for (int j = 0; j < 4; ++j) wv[j] = *(const f32x2*)&wt[cc][2 * ep + 64 * j];
#pragma unroll
            for (int pi = 0; pi < 4; ++pi) {
                f32x2 xsp = {xa[pi], xa[pi]};
#pragma unroll
                for (int j = 0; j < 4; ++j) {
                    f32x2 m = wv[j] * xsp;       // pk_mul (rounded)
                    acc[pi][j] = acc[pi][j] + m;  // pk_add (rounded) — contract off
                }
            }
        }
    }
    __syncthreads();   // all wt reads done before aliasing writes
    float* zs = &wt[0][0];   // [32][260]
    f32x2 b2[4];
#pragma unroll
    for (int j = 0; j < 4; ++j) b2[j] = *(const f32x2*)&bpre[2 * ep + 64 * j];
#pragma unroll
    for (int pi = 0; pi < 4; ++pi) {
        int row = pg * 4 + pi;
#pragma unroll
        for (int j = 0; j < 4; ++j) {
            f32x2 o = acc[pi][j] + b2[j];
            *(f32x2*)&z32[(size_t)(n0 + row) * 256 + 2 * ep + 64 * j] = o;
            *(f32x2*)&zs[row * 260 + 2 * ep + 64 * j] = o;
        }
    }
    __syncthreads();
#pragma unroll
    for (int q = 0; q < 4; ++q) {
        int uid = q * 256 + t;
        int l = uid & 63, ks = (uid >> 6) & 7, tile = uid >> 9;
        int rowl = tile * 16 + (l & 15), colb = ks * 32 + (l >> 4) * 8;
        const float* s = &zs[rowl * 260 + colb];
        float4 a = *(const float4*)s, bb = *(const float4*)(s + 4);
        u16x8 o;
        o[0] = f2bf(a.x); o[1] = f2bf(a.y); o[2] = f2bf(a.z); o[3] = f2bf(a.w);
        o[4] = f2bf(bb.x); o[5] = f2bf(bb.y); o[6] = f2bf(bb.z); o[7] = f2bf(bb.w);
        *((u16x8*)zbf + (((size_t)((n0 >> 4) + tile) * 8 + ks) * 64 + l)) = o;
    }
    if (t < 32) {
        float a = __fadd_rn(np_sqpair128(&zs[t * 260]), np_sqpair128(&zs[t * 260 + 128]));
        A32[n0 + t] = a;
        thr[n0 + t] = 2.75f * sqrtf(a) * 7.0466e-5f - 1e-6f;
    }
}

// ---------------- cb norms (np pairwise semantics) ----------------
__global__ __launch_bounds__(256) void cb_norms(const float* __restrict__ cb,
                                                float* __restrict__ C32) {
    int v = blockIdx.x * 256 + threadIdx.x;
    const float* r = cb + (size_t)v * 256;
    C32[v] = __fadd_rn(np_sqpair128(r), np_sqpair128(r + 128));
}

// ---------------- fragment-layout bf16 builder (codebook) ----------------
__global__ __launch_bounds__(256) void build_frag(const float* __restrict__ src,
                                                  unsigned short* __restrict__ dst) {
    int gid = blockIdx.x * 256 + threadIdx.x;
    int l = gid & 63, ks = (gid >> 6) & 7, tile = gid >> 9;
    int row = tile * 16 + (l & 15);
    int k = ks * 32 + (l >> 4) * 8;
    const float* s = src + (size_t)row * 256 + k;
    float4 a = *(const float4*)s, b = *(const float4*)(s + 4);
    u16x8 o;
    o[0] = f2bf(a.x); o[1] = f2bf(a.y); o[2] = f2bf(a.z); o[3] = f2bf(a.w);
    o[4] = f2bf(b.x); o[5] = f2bf(b.y); o[6] = f2bf(b.z); o[7] = f2bf(b.w);
    *((u16x8*)dst + gid) = o;
}

// ---------------- Stage 2: MFMA screen v4 (AGPR-resident zf) ----------------
// r7 post-mortem: "+v" pin still spilled zf to scratch (VGPR=96, WRITE_SIZE 13.7MB).
// gfx950 MFMA reads A/B directly from AGPRs (unified file); the AGPR side is idle
// (only 16 acc C/D regs), so "+a" pins give zf a contention-free home: 32 x 4 AGPRs.
__global__ __launch_bounds__(512, 2) void screen(const unsigned short* __restrict__ zbf,
                                                 const unsigned short* __restrict__ cbf,
                                                 const float* __restrict__ C32,
                                                 const float* __restrict__ thr,
                                                 int* __restrict__ cnt,
                                                 int* __restrict__ cand) {
    __shared__ __align__(16) char lds[2][65536];
    int t = threadIdx.x, w = t >> 6, l = t & 63;
    int bid = blockIdx.x;
    int rowblk = bid & 31, vblk = bid >> 5;
    int rb = rowblk * 512 + w * 64;

    const char* cbase = (const char*)cbf + (size_t)vblk * 524288;
    {   // issue phase-0 staging first so it overlaps the zf loads below
#pragma unroll
        for (int q = 0; q < 8; ++q)
            gload_lds16(cbase + q * 8192 + t * 16, &lds[0][0] + q * 8192 + t * 16);
    }

    // z fragments: 32 x bf16x8 = 128 regs, pinned to AGPRs ("+a") so the vector-RA
    // cannot spill them to scratch; MFMA consumes B operands from AGPR directly.
    bf16x8 zf[4][8];
#pragma unroll
    for (int tt = 0; tt < 4; ++tt)
#pragma unroll
        for (int ks = 0; ks < 8; ++ks) {
            zf[tt][ks] = *((const bf16x8*)zbf + (((size_t)((rb >> 4) + tt) * 8 + ks) * 64 + l));
            asm volatile("" : "+a"(zf[tt][ks]));
        }

    int   rown[4];
    float thrv[4];
#pragma unroll
    for (int tt = 0; tt < 4; ++tt) {
        rown[tt] = rb + tt * 16 + (l & 15);
        thrv[tt] = thr[rown[tt]];
    }
    __syncthreads();

    for (int p = 0; p < 8; ++p) {
        int cur = p & 1;
        if (p < 7) {
            const char* src = cbase + (size_t)(p + 1) * 65536;
            char* dst = &lds[cur ^ 1][0];
#pragma unroll
            for (int q = 0; q < 8; ++q)
                gload_lds16(src + q * 8192 + t * 16, dst + q * 8192 + t * 16);
        }
        const char* buf = &lds[cur][0];
#pragma unroll 2
        for (int vt = 0; vt < 8; ++vt) {
            f32x4 acc[4];
#pragma unroll
            for (int tt = 0; tt < 4; ++tt) acc[tt] = (f32x4){0.f, 0.f, 0.f, 0.f};
#pragma unroll
            for (int ks = 0; ks < 8; ++ks) {
                bf16x8 af = *(const bf16x8*)(buf + vt * 8192 + ks * 1024 + l * 16);
#pragma unroll
                for (int tt = 0; tt < 4; ++tt)
                    acc[tt] = __builtin_amdgcn_mfma_f32_16x16x32_bf16(af, zf[tt][ks], acc[tt], 0, 0, 0);
            }
            int v0 = vblk * 1024 + p * 128 + vt * 16 + (l >> 4) * 4;
            float4 c4 = *(const float4*)&C32[v0];
            float cv[4] = {c4.x, c4.y, c4.z, c4.w};
#pragma unroll
            for (int tt = 0; tt < 4; ++tt)
#pragma unroll
                for (int j = 0; j < 4; ++j) {
                    float s = __fmaf_rn(-0.5f, cv[j], acc[tt][j]);
                    if (s > thrv[tt]) {
                        int slot = atomicAdd(&cnt[rown[tt]], 1);
                        if (slot < 64) cand[(size_t)rown[tt] * 64 + slot] = v0 + j;
                    }
                }
        }
        __syncthreads();
    }
}

// ---------------- Stage 3: exact np-f32 re-rank (order-independent) ----------------
__global__ __launch_bounds__(256) void rerank(const float* __restrict__ z32,
                                              const float* __restrict__ cb,
                                              const float* __restrict__ A32,
                                              const float* __restrict__ C32,
                                              const int* __restrict__ cand,
                                              const int* __restrict__ cnt,
                                              int* __restrict__ tok_i,
                                              float* __restrict__ tok_f) {
    int row = blockIdx.x * 4 + (threadIdx.x >> 6);
    int l = threadIdx.x & 63;
    int n = cnt[row]; if (n > 64) n = 64;
    float d = 3.4e38f; int v = 0x7fffffff;
    if (l < n) {
        v = cand[(size_t)row * 64 + l];
        const float* zr = z32 + (size_t)row * 256;
        const float* cr = cb + (size_t)v * 256;
        float s = 0.0f;
#pragma unroll 8
        for (int k = 0; k < 256; ++k)
            s = __fmaf_rn(cr[k], zr[k], s);   // strictly ascending k (r2-verified chain)
        d = __fadd_rn(__fsub_rn(A32[row], __fmul_rn(2.0f, s)), C32[v]);
    }
#pragma unroll
    for (int off = 32; off > 0; off >>= 1) {
        float d2 = __shfl_xor(d, off, 64);
        int   v2 = __shfl_xor(v, off, 64);
        if (d2 < d || (d2 == d && v2 < v)) { d = d2; v = v2; }
    }
    if (l == 0) { tok_i[row] = v; tok_f[row] = (float)v; }
}

// ---------------- Stage 4: rec = codebook[tok] @ W_post^T + b_post ----------------
__global__ __launch_bounds__(256) void post_quant(const float* __restrict__ cb,
                                                  const float* __restrict__ Wpost,
                                                  const float* __restrict__ bpost,
                                                  const int* __restrict__ tok,
                                                  float* __restrict__ rec) {
    __shared__ float zq[256][36];   // [e][pix]
    __shared__ float wt[32][260];   // [e-chunk][cout]
    int n0 = blockIdx.x * 32;
    int b = n0 >> 8, pix0 = n0 & 255;
    int t = threadIdx.x;
    int ep = t & 31, pg = t >> 5;

    {   int pix = t & 31, eg = t >> 5;
        int tv = tok[n0 + pix];
        const float* cr = cb + (size_t)tv * 256 + eg * 32;
#pragma unroll
        for (int i = 0; i < 32; ++i)
            zq[eg * 32 + i][pix] = cr[i];
    }

    f32x2 acc[8][2];
#pragma unroll
    for (int s = 0; s < 8; ++s) { acc[s][0] = (f32x2){0.f, 0.f}; acc[s][1] = (f32x2){0.f, 0.f}; }

    for (int e0 = 0; e0 < 256; e0 += 32) {
        __syncthreads();
        const float* wr = Wpost + (size_t)t * 256 + e0;
#pragma unroll
        for (int i = 0; i < 32; i += 4) {
            float4 v = *(const float4*)&wr[i];
            wt[i + 0][t] = v.x; wt[i + 1][t] = v.y;
            wt[i + 2][t] = v.z; wt[i + 3][t] = v.w;
        }
        __syncthreads();
#pragma unroll 8
        for (int ee = 0; ee < 32; ++ee) {
            float4 zv = *(const float4*)&zq[e0 + ee][pg * 4];
            f32x2 zp0 = {zv.x, zv.y}, zp1 = {zv.z, zv.w};
#pragma unroll
            for (int J = 0; J < 4; ++J) {
                f32x2 wv = *(const f32x2*)&wt[ee][2 * ep + 64 * J];
                f32x2 w0 = {wv[0], wv[0]}, w1 = {wv[1], wv[1]};
                acc[2 * J + 0][0] = w0 * zp0 + acc[2 * J + 0][0];
                acc[2 * J + 0][1] = w0 * zp1 + acc[2 * J + 0][1];
                acc[2 * J + 1][0] = w1 * zp0 + acc[2 * J + 1][0];
                acc[2 * J + 1][1] = w1 * zp1 + acc[2 * J + 1][1];
            }
        }
    }
#pragma unroll
    for (int J = 0; J < 4; ++J)
#pragma unroll
        for (int c01 = 0; c01 < 2; ++c01) {
            int cout = 2 * ep + 64 * J + c01;
            float bv = bpost[cout];
            f32x2 bs = {bv, bv};
            f32x2 o0 = acc[2 * J + c01][0] + bs, o1 = acc[2 * J + c01][1] + bs;
            float4 ov = {o0[0], o0[1], o1[0], o1[1]};
            *(float4*)&rec[(size_t)b * 65536 + (size_t)cout * 256 + pix0 + pg * 4] = ov;
        }
}

// ---------------- Launch ----------------
extern "C" void kernel_launch(void* const* d_in, const int* in_sizes, int n_in,
                              void* d_out, int out_size, void* d_ws, size_t ws_size,
                              hipStream_t stream) {
    const float* x     = (const float*)d_in[0];
    const float* Wpre  = (const float*)d_in[1];
    const float* bpre  = (const float*)d_in[2];
    const float* cb    = (const float*)d_in[3];
    const float* Wpost = (const float*)d_in[4];
    const float* bpost = (const float*)d_in[5];

    float* out   = (float*)d_out;
    float* rec   = out;
    float* tok_f = out + 4194304;
    float* z32   = rec;   // z lives in rec region until post_quant overwrites it

    char* ws = (char*)d_ws;
    float*          A32   = (float*)(ws + 0);         // 64 KiB
    float*          C32   = (float*)(ws + 65536);     // 32 KiB
    int*            tok_i = (int*)(ws + 98304);       // 64 KiB
    float*          thr   = (float*)(ws + 163840);    // 64 KiB
    int*            cnt   = (int*)(ws + 229376);      // 64 KiB
    int*            cand  = (int*)(ws + 294912);      // 4 MiB
    unsigned short* zbf   = (unsigned short*)(ws + 4489216);   // 8 MiB
    unsigned short* cbf   = (unsigned short*)(ws + 12877824);  // 4 MiB

    pre_quant_fused<<<NPIX / 32, 256, 0, stream>>>(x, Wpre, bpre, z32, zbf, A32, thr);
    cb_norms<<<VDIM / 256, 256, 0, stream>>>(cb, C32);
    build_frag<<<(VDIM / 16) * 8 * 64 / 256, 256, 0, stream>>>(cb, cbf);
    hipMemsetAsync(cnt, 0, NPIX * sizeof(int), stream);
    screen<<<256, 512, 0, stream>>>(zbf, cbf, C32, thr, cnt, cand);
    rerank<<<NPIX / 4, 256, 0, stream>>>(z32, cb, A32, C32, cand, cnt, tok_i, tok_f);
    post_quant<<<NPIX / 32, 256, 0, stream>>>(cb, Wpost, bpost, tok_i, rec);
}

// Round 9
// 294.865 us; speedup vs baseline: 1.1678x; 1.1678x over previous
//
#include <hip/hip_runtime.h>
#include <cstdint>
#include <cstddef>

#define EDIM 256
#define VDIM 8192
#define NPIX 16384
#define QCAP 512

typedef __attribute__((ext_vector_type(8))) short          bf16x8;
typedef __attribute__((ext_vector_type(8))) unsigned short u16x8;
typedef __attribute__((ext_vector_type(4))) float          f32x4;
typedef __attribute__((ext_vector_type(2))) float          f32x2;

// RNE float->bf16
__device__ __forceinline__ unsigned short f2bf(float x) {
    unsigned int u = __float_as_uint(x);
    return (unsigned short)((u + 0x7fffu + ((u >> 16) & 1u)) >> 16);
}

__device__ __forceinline__ void gload_lds16(const void* gsrc, void* ldst) {
#if defined(__has_builtin) && __has_builtin(__builtin_amdgcn_global_load_lds)
    __builtin_amdgcn_global_load_lds(
        (const __attribute__((address_space(1))) unsigned int*)gsrc,
        (__attribute__((address_space(3))) unsigned int*)ldst, 16, 0, 0);
#else
    *(float4*)ldst = *(const float4*)gsrc;
#endif
}

// ---------- numpy pairwise sum-of-squares (exact semantics, verified r2) ----------
__device__ __forceinline__ float np_sqpair128(const float* __restrict__ z) {
    float r[8];
#pragma unroll
    for (int j = 0; j < 8; ++j) r[j] = __fmul_rn(z[j], z[j]);
    for (int i = 8; i < 128; i += 8) {
#pragma unroll
        for (int j = 0; j < 8; ++j)
            r[j] = __fadd_rn(r[j], __fmul_rn(z[i + j], z[i + j]));
    }
    float t01 = __fadd_rn(r[0], r[1]), t23 = __fadd_rn(r[2], r[3]);
    float t45 = __fadd_rn(r[4], r[5]), t67 = __fadd_rn(r[6], r[7]);
    return __fadd_rn(__fadd_rn(t01, t23), __fadd_rn(t45, t67));
}

// ---------------- Stage 1 (FUSED): z32 + zbf frags + A32 + thr ----------------
__global__ __launch_bounds__(256) void pre_quant_fused(const float* __restrict__ x,
                                                       const float* __restrict__ Wpre,
                                                       const float* __restrict__ bpre,
                                                       float* __restrict__ z32,
                                                       unsigned short* __restrict__ zbf,
                                                       float* __restrict__ A32,
                                                       float* __restrict__ thr) {
#pragma clang fp contract(off)
    __shared__ float xs[32][36];
    __shared__ float wt[32][260];   // [c][e]; aliased as zs[32][260] in epilogue
    int n0 = blockIdx.x * 32;
    int b = n0 >> 8, pix0 = n0 & 255;
    int t = threadIdx.x;
    int ep = t & 31, pg = t >> 5;

    f32x2 acc[4][4];
#pragma unroll
    for (int pi = 0; pi < 4; ++pi)
#pragma unroll
        for (int j = 0; j < 4; ++j) acc[pi][j] = (f32x2){0.f, 0.f};

    for (int c0 = 0; c0 < 256; c0 += 32) {
        __syncthreads();
        {   int cc = t >> 3, pp = (t & 7) * 4;
            *(float4*)&xs[cc][pp] =
                *(const float4*)&x[(size_t)b * 65536 + (size_t)(c0 + cc) * 256 + pix0 + pp];
        }
        {   const float* wr = Wpre + (size_t)t * 256 + c0;
#pragma unroll
            for (int i = 0; i < 32; i += 4) {
                float4 v = *(const float4*)&wr[i];
                wt[i + 0][t] = v.x; wt[i + 1][t] = v.y;
                wt[i + 2][t] = v.z; wt[i + 3][t] = v.w;
            }
        }
        __syncthreads();
#pragma unroll 8
        for (int cc = 0; cc < 32; ++cc) {
            float4 xv = *(const float4*)&xs[cc][pg * 4];
            float xa[4] = {xv.x, xv.y, xv.z, xv.w};
            f32x2 wv[4];
#pragma unroll
            for (int j = 0; j < 4; ++j) wv[j] = *(const f32x2*)&wt[cc][2 * ep + 64 * j];
#pragma unroll
            for (int pi = 0; pi < 4; ++pi) {
                f32x2 xsp = {xa[pi], xa[pi]};
#pragma unroll
                for (int j = 0; j < 4; ++j) {
                    f32x2 m = wv[j] * xsp;       // pk_mul (rounded)
                    acc[pi][j] = acc[pi][j] + m;  // pk_add (rounded) — contract off
                }
            }
        }
    }
    __syncthreads();   // all wt reads done before aliasing writes
    float* zs = &wt[0][0];   // [32][260]
    f32x2 b2[4];
#pragma unroll
    for (int j = 0; j < 4; ++j) b2[j] = *(const f32x2*)&bpre[2 * ep + 64 * j];
#pragma unroll
    for (int pi = 0; pi < 4; ++pi) {
        int row = pg * 4 + pi;
#pragma unroll
        for (int j = 0; j < 4; ++j) {
            f32x2 o = acc[pi][j] + b2[j];
            *(f32x2*)&z32[(size_t)(n0 + row) * 256 + 2 * ep + 64 * j] = o;
            *(f32x2*)&zs[row * 260 + 2 * ep + 64 * j] = o;
        }
    }
    __syncthreads();
#pragma unroll
    for (int q = 0; q < 4; ++q) {
        int uid = q * 256 + t;
        int l = uid & 63, ks = (uid >> 6) & 7, tile = uid >> 9;
        int rowl = tile * 16 + (l & 15), colb = ks * 32 + (l >> 4) * 8;
        const float* s = &zs[rowl * 260 + colb];
        float4 a = *(const float4*)s, bb = *(const float4*)(s + 4);
        u16x8 o;
        o[0] = f2bf(a.x); o[1] = f2bf(a.y); o[2] = f2bf(a.z); o[3] = f2bf(a.w);
        o[4] = f2bf(bb.x); o[5] = f2bf(bb.y); o[6] = f2bf(bb.z); o[7] = f2bf(bb.w);
        *((u16x8*)zbf + (((size_t)((n0 >> 4) + tile) * 8 + ks) * 64 + l)) = o;
    }
    if (t < 32) {
        float a = __fadd_rn(np_sqpair128(&zs[t * 260]), np_sqpair128(&zs[t * 260 + 128]));
        A32[n0 + t] = a;
        thr[n0 + t] = 2.75f * sqrtf(a) * 7.0466e-5f - 1e-6f;
    }
}

// ---------------- cb norms (np pairwise semantics) ----------------
__global__ __launch_bounds__(256) void cb_norms(const float* __restrict__ cb,
                                                float* __restrict__ C32) {
    int v = blockIdx.x * 256 + threadIdx.x;
    const float* r = cb + (size_t)v * 256;
    C32[v] = __fadd_rn(np_sqpair128(r), np_sqpair128(r + 128));
}

// ---------------- fragment-layout bf16 builder (codebook) ----------------
__global__ __launch_bounds__(256) void build_frag(const float* __restrict__ src,
                                                  unsigned short* __restrict__ dst) {
    int gid = blockIdx.x * 256 + threadIdx.x;
    int l = gid & 63, ks = (gid >> 6) & 7, tile = gid >> 9;
    int row = tile * 16 + (l & 15);
    int k = ks * 32 + (l >> 4) * 8;
    const float* s = src + (size_t)row * 256 + k;
    float4 a = *(const float4*)s, b = *(const float4*)(s + 4);
    u16x8 o;
    o[0] = f2bf(a.x); o[1] = f2bf(a.y); o[2] = f2bf(a.z); o[3] = f2bf(a.w);
    o[4] = f2bf(b.x); o[5] = f2bf(b.y); o[6] = f2bf(b.z); o[7] = f2bf(b.w);
    *((u16x8*)dst + gid) = o;
}

// ---------------- Stage 2: MFMA screen v5 (no in-loop atomics) ----------------
// r8 post-mortem: ~195 return-value atomicAdds per wave in the inner loop = ~80k+
// cyc of exposed vmem-wait per wave. v5: ballot -> uniform SGPR counter + mbcnt
// index -> per-wave LDS queue append (no memory atomic); one flush at kernel end.
// XCD 2D tile: XCD x = bid&7 gets 8 rowblks x 4 vblks -> 2 MiB zbf + 2 MiB cbf = L2-fit.
__global__ __launch_bounds__(512, 2) void screen(const unsigned short* __restrict__ zbf,
                                                 const unsigned short* __restrict__ cbf,
                                                 const float* __restrict__ C32,
                                                 const float* __restrict__ thr,
                                                 int* __restrict__ cnt,
                                                 int* __restrict__ cand) {
    __shared__ __align__(16) char lds[2][65536];
    __shared__ unsigned q[8][QCAP];   // 16 KiB per-wave candidate queues
    int t = threadIdx.x, w = t >> 6, l = t & 63;
    int bid = blockIdx.x;
    int x = bid & 7, k = bid >> 3;
    int rowblk = (x & 3) * 8 + (k & 7);
    int vblk   = (x >> 2) * 4 + (k >> 3);
    int rb = rowblk * 512 + w * 64;

    const char* cbase = (const char*)cbf + (size_t)vblk * 524288;
    {   // issue phase-0 staging first so it overlaps the zf loads below
#pragma unroll
        for (int qq = 0; qq < 8; ++qq)
            gload_lds16(cbase + qq * 8192 + t * 16, &lds[0][0] + qq * 8192 + t * 16);
    }

    bf16x8 zf[4][8];
#pragma unroll
    for (int tt = 0; tt < 4; ++tt)
#pragma unroll
        for (int ks = 0; ks < 8; ++ks) {
            zf[tt][ks] = *((const bf16x8*)zbf + (((size_t)((rb >> 4) + tt) * 8 + ks) * 64 + l));
            asm volatile("" : "+a"(zf[tt][ks]));
        }

    int   rown[4];
    float thrv[4];
#pragma unroll
    for (int tt = 0; tt < 4; ++tt) {
        rown[tt] = rb + tt * 16 + (l & 15);
        thrv[tt] = thr[rown[tt]];
    }
    int wcnt = 0;   // uniform across wave (updated from ballot popcounts) -> SGPR
    __syncthreads();

    for (int p = 0; p < 8; ++p) {
        int cur = p & 1;
        if (p < 7) {
            const char* src = cbase + (size_t)(p + 1) * 65536;
            char* dst = &lds[cur ^ 1][0];
#pragma unroll
            for (int qq = 0; qq < 8; ++qq)
                gload_lds16(src + qq * 8192 + t * 16, dst + qq * 8192 + t * 16);
        }
        const char* buf = &lds[cur][0];
#pragma unroll 2
        for (int vt = 0; vt < 8; ++vt) {
            f32x4 acc[4];
#pragma unroll
            for (int tt = 0; tt < 4; ++tt) acc[tt] = (f32x4){0.f, 0.f, 0.f, 0.f};
#pragma unroll
            for (int ks = 0; ks < 8; ++ks) {
                bf16x8 af = *(const bf16x8*)(buf + vt * 8192 + ks * 1024 + l * 16);
#pragma unroll
                for (int tt = 0; tt < 4; ++tt)
                    acc[tt] = __builtin_amdgcn_mfma_f32_16x16x32_bf16(af, zf[tt][ks], acc[tt], 0, 0, 0);
            }
            int v0 = vblk * 1024 + p * 128 + vt * 16 + (l >> 4) * 4;
            float4 c4 = *(const float4*)&C32[v0];
            float cv[4] = {c4.x, c4.y, c4.z, c4.w};
#pragma unroll
            for (int tt = 0; tt < 4; ++tt)
#pragma unroll
                for (int j = 0; j < 4; ++j) {
                    float s = __fmaf_rn(-0.5f, cv[j], acc[tt][j]);
                    bool fire = s > thrv[tt];
                    unsigned long long m = __ballot(fire);
                    if (m) {   // uniform branch; ~19% of checks
                        int my = wcnt + __builtin_amdgcn_mbcnt_hi(
                                     (unsigned)(m >> 32),
                                     __builtin_amdgcn_mbcnt_lo((unsigned)m, 0));
                        if (fire) {
                            unsigned pk = ((unsigned)rown[tt] << 13) | (unsigned)(v0 + j);
                            if (my < QCAP) q[w][my] = pk;
                            else {   // astronomically rare overflow: direct append
                                int sl = atomicAdd(&cnt[rown[tt]], 1);
                                if (sl < 64) cand[(size_t)rown[tt] * 64 + sl] = v0 + j;
                            }
                        }
                        wcnt += __popcll(m);
                    }
                }
        }
        __syncthreads();
    }

    // per-wave flush: queue -> global (atomic latency exposed once, not per fire)
    int nq = wcnt < QCAP ? wcnt : QCAP;
    for (int i = l; i < nq; i += 64) {
        unsigned pk = q[w][i];
        int row = pk >> 13, v = pk & 8191;
        int sl = atomicAdd(&cnt[row], 1);
        if (sl < 64) cand[(size_t)row * 64 + sl] = v;
    }
}

// ---------------- Stage 3: exact np-f32 re-rank (order-independent) ----------------
__global__ __launch_bounds__(256) void rerank(const float* __restrict__ z32,
                                              const float* __restrict__ cb,
                                              const float* __restrict__ A32,
                                              const float* __restrict__ C32,
                                              const int* __restrict__ cand,
                                              const int* __restrict__ cnt,
                                              int* __restrict__ tok_i,
                                              float* __restrict__ tok_f) {
    int row = blockIdx.x * 4 + (threadIdx.x >> 6);
    int l = threadIdx.x & 63;
    int n = cnt[row]; if (n > 64) n = 64;
    float d = 3.4e38f; int v = 0x7fffffff;
    if (l < n) {
        v = cand[(size_t)row * 64 + l];
        const float* zr = z32 + (size_t)row * 256;
        const float* cr = cb + (size_t)v * 256;
        float s = 0.0f;
#pragma unroll 8
        for (int k = 0; k < 256; ++k)
            s = __fmaf_rn(cr[k], zr[k], s);   // strictly ascending k (r2-verified chain)
        d = __fadd_rn(__fsub_rn(A32[row], __fmul_rn(2.0f, s)), C32[v]);
    }
#pragma unroll
    for (int off = 32; off > 0; off >>= 1) {
        float d2 = __shfl_xor(d, off, 64);
        int   v2 = __shfl_xor(v, off, 64);
        if (d2 < d || (d2 == d && v2 < v)) { d = d2; v = v2; }
    }
    if (l == 0) { tok_i[row] = v; tok_f[row] = (float)v; }
}

// ---------------- Stage 4: rec = codebook[tok] @ W_post^T + b_post ----------------
__global__ __launch_bounds__(256) void post_quant(const float* __restrict__ cb,
                                                  const float* __restrict__ Wpost,
                                                  const float* __restrict__ bpost,
                                                  const int* __restrict__ tok,
                                                  float* __restrict__ rec) {
    __shared__ float zq[256][36];   // [e][pix]
    __shared__ float wt[32][260];   // [e-chunk][cout]
    int n0 = blockIdx.x * 32;
    int b = n0 >> 8, pix0 = n0 & 255;
    int t = threadIdx.x;
    int ep = t & 31, pg = t >> 5;

    {   int pix = t & 31, eg = t >> 5;
        int tv = tok[n0 + pix];
        const float* cr = cb + (size_t)tv * 256 + eg * 32;
#pragma unroll
        for (int i = 0; i < 32; ++i)
            zq[eg * 32 + i][pix] = cr[i];
    }

    f32x2 acc[8][2];
#pragma unroll
    for (int s = 0; s < 8; ++s) { acc[s][0] = (f32x2){0.f, 0.f}; acc[s][1] = (f32x2){0.f, 0.f}; }

    for (int e0 = 0; e0 < 256; e0 += 32) {
        __syncthreads();
        const float* wr = Wpost + (size_t)t * 256 + e0;
#pragma unroll
        for (int i = 0; i < 32; i += 4) {
            float4 v = *(const float4*)&wr[i];
            wt[i + 0][t] = v.x; wt[i + 1][t] = v.y;
            wt[i + 2][t] = v.z; wt[i + 3][t] = v.w;
        }
        __syncthreads();
#pragma unroll 8
        for (int ee = 0; ee < 32; ++ee) {
            float4 zv = *(const float4*)&zq[e0 + ee][pg * 4];
            f32x2 zp0 = {zv.x, zv.y}, zp1 = {zv.z, zv.w};
#pragma unroll
            for (int J = 0; J < 4; ++J) {
                f32x2 wv = *(const f32x2*)&wt[ee][2 * ep + 64 * J];
                f32x2 w0 = {wv[0], wv[0]}, w1 = {wv[1], wv[1]};
                acc[2 * J + 0][0] = w0 * zp0 + acc[2 * J + 0][0];
                acc[2 * J + 0][1] = w0 * zp1 + acc[2 * J + 0][1];
                acc[2 * J + 1][0] = w1 * zp0 + acc[2 * J + 1][0];
                acc[2 * J + 1][1] = w1 * zp1 + acc[2 * J + 1][1];
            }
        }
    }
#pragma unroll
    for (int J = 0; J < 4; ++J)
#pragma unroll
        for (int c01 = 0; c01 < 2; ++c01) {
            int cout = 2 * ep + 64 * J + c01;
            float bv = bpost[cout];
            f32x2 bs = {bv, bv};
            f32x2 o0 = acc[2 * J + c01][0] + bs, o1 = acc[2 * J + c01][1] + bs;
            float4 ov = {o0[0], o0[1], o1[0], o1[1]};
            *(float4*)&rec[(size_t)b * 65536 + (size_t)cout * 256 + pix0 + pg * 4] = ov;
        }
}

// ---------------- Launch ----------------
extern "C" void kernel_launch(void* const* d_in, const int* in_sizes, int n_in,
                              void* d_out, int out_size, void* d_ws, size_t ws_size,
                              hipStream_t stream) {
    const float* x     = (const float*)d_in[0];
    const float* Wpre  = (const float*)d_in[1];
    const float* bpre  = (const float*)d_in[2];
    const float* cb    = (const float*)d_in[3];
    const float* Wpost = (const float*)d_in[4];
    const float* bpost = (const float*)d_in[5];

    float* out   = (float*)d_out;
    float* rec   = out;
    float* tok_f = out + 4194304;
    float* z32   = rec;   // z lives in rec region until post_quant overwrites it

    char* ws = (char*)d_ws;
    float*          A32   = (float*)(ws + 0);         // 64 KiB
    float*          C32   = (float*)(ws + 65536);     // 32 KiB
    int*            tok_i = (int*)(ws + 98304);       // 64 KiB
    float*          thr   = (float*)(ws + 163840);    // 64 KiB
    int*            cnt   = (int*)(ws + 229376);      // 64 KiB
    int*            cand  = (int*)(ws + 294912);      // 4 MiB
    unsigned short* zbf   = (unsigned short*)(ws + 4489216);   // 8 MiB
    unsigned short* cbf   = (unsigned short*)(ws + 12877824);  // 4 MiB

    pre_quant_fused<<<NPIX / 32, 256, 0, stream>>>(x, Wpre, bpre, z32, zbf, A32, thr);
    cb_norms<<<VDIM / 256, 256, 0, stream>>>(cb, C32);
    build_frag<<<(VDIM / 16) * 8 * 64 / 256, 256, 0, stream>>>(cb, cbf);
    hipMemsetAsync(cnt, 0, NPIX * sizeof(int), stream);
    screen<<<256, 512, 0, stream>>>(zbf, cbf, C32, thr, cnt, cand);
    rerank<<<NPIX / 4, 256, 0, stream>>>(z32, cb, A32, C32, cand, cnt, tok_i, tok_f);
    post_quant<<<NPIX / 32, 256, 0, stream>>>(cb, Wpost, bpost, tok_i, rec);
}

// Round 10
// 291.891 us; speedup vs baseline: 1.1797x; 1.0102x over previous
//
#include <hip/hip_runtime.h>
#include <cstdint>
#include <cstddef>

#define EDIM 256
#define VDIM 8192
#define NPIX 16384
#define QCAP 512

typedef __attribute__((ext_vector_type(8))) short          bf16x8;
typedef __attribute__((ext_vector_type(8))) unsigned short u16x8;
typedef __attribute__((ext_vector_type(4))) float          f32x4;
typedef __attribute__((ext_vector_type(2))) float          f32x2;

// RNE float->bf16
__device__ __forceinline__ unsigned short f2bf(float x) {
    unsigned int u = __float_as_uint(x);
    return (unsigned short)((u + 0x7fffu + ((u >> 16) & 1u)) >> 16);
}

__device__ __forceinline__ void gload_lds16(const void* gsrc, void* ldst) {
#if defined(__has_builtin) && __has_builtin(__builtin_amdgcn_global_load_lds)
    __builtin_amdgcn_global_load_lds(
        (const __attribute__((address_space(1))) unsigned int*)gsrc,
        (__attribute__((address_space(3))) unsigned int*)ldst, 16, 0, 0);
#else
    *(float4*)ldst = *(const float4*)gsrc;
#endif
}

// ---------- numpy pairwise sum-of-squares (exact semantics, verified r2) ----------
__device__ __forceinline__ float np_sqpair128(const float* __restrict__ z) {
    float r[8];
#pragma unroll
    for (int j = 0; j < 8; ++j) r[j] = __fmul_rn(z[j], z[j]);
    for (int i = 8; i < 128; i += 8) {
#pragma unroll
        for (int j = 0; j < 8; ++j)
            r[j] = __fadd_rn(r[j], __fmul_rn(z[i + j], z[i + j]));
    }
    float t01 = __fadd_rn(r[0], r[1]), t23 = __fadd_rn(r[2], r[3]);
    float t45 = __fadd_rn(r[4], r[5]), t67 = __fadd_rn(r[6], r[7]);
    return __fadd_rn(__fadd_rn(t01, t23), __fadd_rn(t45, t67));
}

// ---------------- Stage 1 (FUSED): z32 + zbf frags + A32 + thr ----------------
__global__ __launch_bounds__(256) void pre_quant_fused(const float* __restrict__ x,
                                                       const float* __restrict__ Wpre,
                                                       const float* __restrict__ bpre,
                                                       float* __restrict__ z32,
                                                       unsigned short* __restrict__ zbf,
                                                       float* __restrict__ A32,
                                                       float* __restrict__ thr) {
#pragma clang fp contract(off)
    __shared__ float xs[32][36];
    __shared__ float wt[32][260];   // [c][e]; aliased as zs[32][260] in epilogue
    int n0 = blockIdx.x * 32;
    int b = n0 >> 8, pix0 = n0 & 255;
    int t = threadIdx.x;
    int ep = t & 31, pg = t >> 5;

    f32x2 acc[4][4];
#pragma unroll
    for (int pi = 0; pi < 4; ++pi)
#pragma unroll
        for (int j = 0; j < 4; ++j) acc[pi][j] = (f32x2){0.f, 0.f};

    for (int c0 = 0; c0 < 256; c0 += 32) {
        __syncthreads();
        {   int cc = t >> 3, pp = (t & 7) * 4;
            *(float4*)&xs[cc][pp] =
                *(const float4*)&x[(size_t)b * 65536 + (size_t)(c0 + cc) * 256 + pix0 + pp];
        }
        {   const float* wr = Wpre + (size_t)t * 256 + c0;
#pragma unroll
            for (int i = 0; i < 32; i += 4) {
                float4 v = *(const float4*)&wr[i];
                wt[i + 0][t] = v.x; wt[i + 1][t] = v.y;
                wt[i + 2][t] = v.z; wt[i + 3][t] = v.w;
            }
        }
        __syncthreads();
#pragma unroll 8
        for (int cc = 0; cc < 32; ++cc) {
            float4 xv = *(const float4*)&xs[cc][pg * 4];
            float xa[4] = {xv.x, xv.y, xv.z, xv.w};
            f32x2 wv[4];
#pragma unroll
            for (int j = 0; j < 4; ++j) wv[j] = *(const f32x2*)&wt[cc][2 * ep + 64 * j];
#pragma unroll
            for (int pi = 0; pi < 4; ++pi) {
                f32x2 xsp = {xa[pi], xa[pi]};
#pragma unroll
                for (int j = 0; j < 4; ++j) {
                    f32x2 m = wv[j] * xsp;       // pk_mul (rounded)
                    acc[pi][j] = acc[pi][j] + m;  // pk_add (rounded) — contract off
                }
            }
        }
    }
    __syncthreads();   // all wt reads done before aliasing writes
    float* zs = &wt[0][0];   // [32][260]
    f32x2 b2[4];
#pragma unroll
    for (int j = 0; j < 4; ++j) b2[j] = *(const f32x2*)&bpre[2 * ep + 64 * j];
#pragma unroll
    for (int pi = 0; pi < 4; ++pi) {
        int row = pg * 4 + pi;
#pragma unroll
        for (int j = 0; j < 4; ++j) {
            f32x2 o = acc[pi][j] + b2[j];
            *(f32x2*)&z32[(size_t)(n0 + row) * 256 + 2 * ep + 64 * j] = o;
            *(f32x2*)&zs[row * 260 + 2 * ep + 64 * j] = o;
        }
    }
    __syncthreads();
#pragma unroll
    for (int q = 0; q < 4; ++q) {
        int uid = q * 256 + t;
        int l = uid & 63, ks = (uid >> 6) & 7, tile = uid >> 9;
        int rowl = tile * 16 + (l & 15), colb = ks * 32 + (l >> 4) * 8;
        const float* s = &zs[rowl * 260 + colb];
        float4 a = *(const float4*)s, bb = *(const float4*)(s + 4);
        u16x8 o;
        o[0] = f2bf(a.x); o[1] = f2bf(a.y); o[2] = f2bf(a.z); o[3] = f2bf(a.w);
        o[4] = f2bf(bb.x); o[5] = f2bf(bb.y); o[6] = f2bf(bb.z); o[7] = f2bf(bb.w);
        *((u16x8*)zbf + (((size_t)((n0 >> 4) + tile) * 8 + ks) * 64 + l)) = o;
    }
    if (t < 32) {
        float a = __fadd_rn(np_sqpair128(&zs[t * 260]), np_sqpair128(&zs[t * 260 + 128]));
        A32[n0 + t] = a;
        thr[n0 + t] = 2.75f * sqrtf(a) * 7.0466e-5f - 1e-6f;
    }
}

// ---------------- cb norms (np pairwise semantics) ----------------
__global__ __launch_bounds__(256) void cb_norms(const float* __restrict__ cb,
                                                float* __restrict__ C32) {
    int v = blockIdx.x * 256 + threadIdx.x;
    const float* r = cb + (size_t)v * 256;
    C32[v] = __fadd_rn(np_sqpair128(r), np_sqpair128(r + 128));
}

// ---------------- fragment-layout bf16 builder (codebook) ----------------
__global__ __launch_bounds__(256) void build_frag(const float* __restrict__ src,
                                                  unsigned short* __restrict__ dst) {
    int gid = blockIdx.x * 256 + threadIdx.x;
    int l = gid & 63, ks = (gid >> 6) & 7, tile = gid >> 9;
    int row = tile * 16 + (l & 15);
    int k = ks * 32 + (l >> 4) * 8;
    const float* s = src + (size_t)row * 256 + k;
    float4 a = *(const float4*)s, b = *(const float4*)(s + 4);
    u16x8 o;
    o[0] = f2bf(a.x); o[1] = f2bf(a.y); o[2] = f2bf(a.z); o[3] = f2bf(a.w);
    o[4] = f2bf(b.x); o[5] = f2bf(b.y); o[6] = f2bf(b.z); o[7] = f2bf(b.w);
    *((u16x8*)dst + gid) = o;
}

// ---------------- Stage 2: MFMA screen v5 (no in-loop atomics; r9-validated) ----------------
__global__ __launch_bounds__(512, 2) void screen(const unsigned short* __restrict__ zbf,
                                                 const unsigned short* __restrict__ cbf,
                                                 const float* __restrict__ C32,
                                                 const float* __restrict__ thr,
                                                 int* __restrict__ cnt,
                                                 int* __restrict__ cand) {
    __shared__ __align__(16) char lds[2][65536];
    __shared__ unsigned q[8][QCAP];   // 16 KiB per-wave candidate queues
    int t = threadIdx.x, w = t >> 6, l = t & 63;
    int bid = blockIdx.x;
    int x = bid & 7, k = bid >> 3;
    int rowblk = (x & 3) * 8 + (k & 7);
    int vblk   = (x >> 2) * 4 + (k >> 3);
    int rb = rowblk * 512 + w * 64;

    const char* cbase = (const char*)cbf + (size_t)vblk * 524288;
    {
#pragma unroll
        for (int qq = 0; qq < 8; ++qq)
            gload_lds16(cbase + qq * 8192 + t * 16, &lds[0][0] + qq * 8192 + t * 16);
    }

    bf16x8 zf[4][8];
#pragma unroll
    for (int tt = 0; tt < 4; ++tt)
#pragma unroll
        for (int ks = 0; ks < 8; ++ks) {
            zf[tt][ks] = *((const bf16x8*)zbf + (((size_t)((rb >> 4) + tt) * 8 + ks) * 64 + l));
            asm volatile("" : "+a"(zf[tt][ks]));
        }

    int   rown[4];
    float thrv[4];
#pragma unroll
    for (int tt = 0; tt < 4; ++tt) {
        rown[tt] = rb + tt * 16 + (l & 15);
        thrv[tt] = thr[rown[tt]];
    }
    int wcnt = 0;   // uniform across wave (updated from ballot popcounts) -> SGPR
    __syncthreads();

    for (int p = 0; p < 8; ++p) {
        int cur = p & 1;
        if (p < 7) {
            const char* src = cbase + (size_t)(p + 1) * 65536;
            char* dst = &lds[cur ^ 1][0];
#pragma unroll
            for (int qq = 0; qq < 8; ++qq)
                gload_lds16(src + qq * 8192 + t * 16, dst + qq * 8192 + t * 16);
        }
        const char* buf = &lds[cur][0];
#pragma unroll 2
        for (int vt = 0; vt < 8; ++vt) {
            f32x4 acc[4];
#pragma unroll
            for (int tt = 0; tt < 4; ++tt) acc[tt] = (f32x4){0.f, 0.f, 0.f, 0.f};
#pragma unroll
            for (int ks = 0; ks < 8; ++ks) {
                bf16x8 af = *(const bf16x8*)(buf + vt * 8192 + ks * 1024 + l * 16);
#pragma unroll
                for (int tt = 0; tt < 4; ++tt)
                    acc[tt] = __builtin_amdgcn_mfma_f32_16x16x32_bf16(af, zf[tt][ks], acc[tt], 0, 0, 0);
            }
            int v0 = vblk * 1024 + p * 128 + vt * 16 + (l >> 4) * 4;
            float4 c4 = *(const float4*)&C32[v0];
            float cv[4] = {c4.x, c4.y, c4.z, c4.w};
#pragma unroll
            for (int tt = 0; tt < 4; ++tt)
#pragma unroll
                for (int j = 0; j < 4; ++j) {
                    float s = __fmaf_rn(-0.5f, cv[j], acc[tt][j]);
                    bool fire = s > thrv[tt];
                    unsigned long long m = __ballot(fire);
                    if (m) {   // uniform branch; ~19% of checks
                        int my = wcnt + __builtin_amdgcn_mbcnt_hi(
                                     (unsigned)(m >> 32),
                                     __builtin_amdgcn_mbcnt_lo((unsigned)m, 0));
                        if (fire) {
                            unsigned pk = ((unsigned)rown[tt] << 13) | (unsigned)(v0 + j);
                            if (my < QCAP) q[w][my] = pk;
                            else {   // astronomically rare overflow: direct append
                                int sl = atomicAdd(&cnt[rown[tt]], 1);
                                if (sl < 64) cand[(size_t)rown[tt] * 64 + sl] = v0 + j;
                            }
                        }
                        wcnt += __popcll(m);
                    }
                }
        }
        __syncthreads();
    }

    int nq = wcnt < QCAP ? wcnt : QCAP;
    for (int i = l; i < nq; i += 64) {
        unsigned pk = q[w][i];
        int row = pk >> 13, v = pk & 8191;
        int sl = atomicAdd(&cnt[row], 1);
        if (sl < 64) cand[(size_t)row * 64 + sl] = v;
    }
}

// ---------------- Stage 3: exact np-f32 re-rank v2 (LDS-staged, coalesced) ----------------
// r9 post-mortem: per-lane 1KB codebook gathers = 64-line fanout per vmem instr ->
// latency-bound at 100us. v2: compact the block's <=256 (row,cand) items; per 64-k
// chunk, 16-lane groups stage each candidate's 256B slice COALESCED into LDS
// (stride 65 = odd -> conflict-free chain reads); each thread runs its bit-exact
// ascending-k FMA chain from LDS. Values & order identical -> tokens unchanged.
__global__ __launch_bounds__(256) void rerank(const float* __restrict__ z32,
                                              const float* __restrict__ cb,
                                              const float* __restrict__ A32,
                                              const float* __restrict__ C32,
                                              const int* __restrict__ cand,
                                              const int* __restrict__ cnt,
                                              int* __restrict__ tok_i,
                                              float* __restrict__ tok_f) {
    __shared__ float sbuf[256 * 65];   // [item][65] odd stride: chain reads 2-way max
    __shared__ float zs[4][260];       // z rows (banks offset by 4/row -> conflict-free)
    __shared__ int   sv[256];
    __shared__ int   sh[5];            // row offsets o0..o3, m
    __shared__ float dbuf[4][64];
    __shared__ int   vbuf[4][64];
    int t = threadIdx.x;
    int n0 = blockIdx.x * 4;

    if (t == 0) {
        int o = 0;
#pragma unroll
        for (int r = 0; r < 4; ++r) {
            sh[r] = o;
            int n = cnt[n0 + r]; if (n > 64) n = 64;
            o += n;
        }
        sh[4] = o;
    }
    {   // stage z rows: thread t -> row t>>6, elems (t&63)*4..+3 (coalesced)
        int r = t >> 6, e = (t & 63) * 4;
        *(float4*)&zs[r][e] = *(const float4*)&z32[(size_t)(n0 + r) * 256 + e];
    }
    __syncthreads();
    int o1 = sh[1], o2 = sh[2], o3 = sh[3], m = sh[4];

    int myrow = 0, myv = 0;
    if (t < m) {
        myrow = (t >= o1) + (t >= o2) + (t >= o3);
        int myslot = t - sh[myrow];
        myv = cand[(size_t)(n0 + myrow) * 64 + myslot];
        sv[t] = myv;
    }
    __syncthreads();

    float s = 0.0f;
    for (int c0 = 0; c0 < 256; c0 += 64) {
        if (c0) __syncthreads();   // previous chunk's reads complete
        // cooperative stage: group g=t>>4 handles items i≡g (mod 16); 16 lanes x float4
        for (int i = t >> 4; i < m; i += 16) {
            int v = sv[i];
            float4 wv = *(const float4*)&cb[(size_t)v * 256 + c0 + (t & 15) * 4];
            int base = i * 65 + (t & 15) * 4;
            sbuf[base] = wv.x; sbuf[base + 1] = wv.y;
            sbuf[base + 2] = wv.z; sbuf[base + 3] = wv.w;
        }
        __syncthreads();
        if (t < m) {
            const float* cz = &zs[myrow][c0];
            const float* cs = &sbuf[t * 65];
#pragma unroll 16
            for (int k = 0; k < 64; ++k)
                s = __fmaf_rn(cs[k], cz[k], s);   // strictly ascending k (r2 chain)
        }
    }
    if (t < m) {
        float d = __fadd_rn(__fsub_rn(A32[n0 + myrow], __fmul_rn(2.0f, s)), C32[myv]);
        int myslot = t - sh[myrow];
        dbuf[myrow][myslot] = d;
        vbuf[myrow][myslot] = myv;
    }
    __syncthreads();
    {
        int g = t >> 6, l = t & 63;
        int n = sh[g + 1] - sh[g];
        float d = 3.4e38f; int v = 0x7fffffff;
        if (l < n) { d = dbuf[g][l]; v = vbuf[g][l]; }
#pragma unroll
        for (int off = 32; off > 0; off >>= 1) {
            float d2 = __shfl_xor(d, off, 64);
            int   v2 = __shfl_xor(v, off, 64);
            if (d2 < d || (d2 == d && v2 < v)) { d = d2; v = v2; }
        }
        if (l == 0) { tok_i[n0 + g] = v; tok_f[n0 + g] = (float)v; }
    }
}

// ---------------- Stage 4: rec = codebook[tok] @ W_post^T + b_post ----------------
__global__ __launch_bounds__(256) void post_quant(const float* __restrict__ cb,
                                                  const float* __restrict__ Wpost,
                                                  const float* __restrict__ bpost,
                                                  const int* __restrict__ tok,
                                                  float* __restrict__ rec) {
    __shared__ float zq[256][36];   // [e][pix]
    __shared__ float wt[32][260];   // [e-chunk][cout]
    int n0 = blockIdx.x * 32;
    int b = n0 >> 8, pix0 = n0 & 255;
    int t = threadIdx.x;
    int ep = t & 31, pg = t >> 5;

    {   int pix = t & 31, eg = t >> 5;
        int tv = tok[n0 + pix];
        const float* cr = cb + (size_t)tv * 256 + eg * 32;
#pragma unroll
        for (int i = 0; i < 32; ++i)
            zq[eg * 32 + i][pix] = cr[i];
    }

    f32x2 acc[8][2];
#pragma unroll
    for (int s = 0; s < 8; ++s) { acc[s][0] = (f32x2){0.f, 0.f}; acc[s][1] = (f32x2){0.f, 0.f}; }

    for (int e0 = 0; e0 < 256; e0 += 32) {
        __syncthreads();
        const float* wr = Wpost + (size_t)t * 256 + e0;
#pragma unroll
        for (int i = 0; i < 32; i += 4) {
            float4 v = *(const float4*)&wr[i];
            wt[i + 0][t] = v.x; wt[i + 1][t] = v.y;
            wt[i + 2][t] = v.z; wt[i + 3][t] = v.w;
        }
        __syncthreads();
#pragma unroll 8
        for (int ee = 0; ee < 32; ++ee) {
            float4 zv = *(const float4*)&zq[e0 + ee][pg * 4];
            f32x2 zp0 = {zv.x, zv.y}, zp1 = {zv.z, zv.w};
#pragma unroll
            for (int J = 0; J < 4; ++J) {
                f32x2 wv = *(const f32x2*)&wt[ee][2 * ep + 64 * J];
                f32x2 w0 = {wv[0], wv[0]}, w1 = {wv[1], wv[1]};
                acc[2 * J + 0][0] = w0 * zp0 + acc[2 * J + 0][0];
                acc[2 * J + 0][1] = w0 * zp1 + acc[2 * J + 0][1];
                acc[2 * J + 1][0] = w1 * zp0 + acc[2 * J + 1][0];
                acc[2 * J + 1][1] = w1 * zp1 + acc[2 * J + 1][1];
            }
        }
    }
#pragma unroll
    for (int J = 0; J < 4; ++J)
#pragma unroll
        for (int c01 = 0; c01 < 2; ++c01) {
            int cout = 2 * ep + 64 * J + c01;
            float bv = bpost[cout];
            f32x2 bs = {bv, bv};
            f32x2 o0 = acc[2 * J + c01][0] + bs, o1 = acc[2 * J + c01][1] + bs;
            float4 ov = {o0[0], o0[1], o1[0], o1[1]};
            *(float4*)&rec[(size_t)b * 65536 + (size_t)cout * 256 + pix0 + pg * 4] = ov;
        }
}

// ---------------- Launch ----------------
extern "C" void kernel_launch(void* const* d_in, const int* in_sizes, int n_in,
                              void* d_out, int out_size, void* d_ws, size_t ws_size,
                              hipStream_t stream) {
    const float* x     = (const float*)d_in[0];
    const float* Wpre  = (const float*)d_in[1];
    const float* bpre  = (const float*)d_in[2];
    const float* cb    = (const float*)d_in[3];
    const float* Wpost = (const float*)d_in[4];
    const float* bpost = (const float*)d_in[5];

    float* out   = (float*)d_out;
    float* rec   = out;
    float* tok_f = out + 4194304;
    float* z32   = rec;   // z lives in rec region until post_quant overwrites it

    char* ws = (char*)d_ws;
    float*          A32   = (float*)(ws + 0);         // 64 KiB
    float*          C32   = (float*)(ws + 65536);     // 32 KiB
    int*            tok_i = (int*)(ws + 98304);       // 64 KiB
    float*          thr   = (float*)(ws + 163840);    // 64 KiB
    int*            cnt   = (int*)(ws + 229376);      // 64 KiB
    int*            cand  = (int*)(ws + 294912);      // 4 MiB
    unsigned short* zbf   = (unsigned short*)(ws + 4489216);   // 8 MiB
    unsigned short* cbf   = (unsigned short*)(ws + 12877824);  // 4 MiB

    pre_quant_fused<<<NPIX / 32, 256, 0, stream>>>(x, Wpre, bpre, z32, zbf, A32, thr);
    cb_norms<<<VDIM / 256, 256, 0, stream>>>(cb, C32);
    build_frag<<<(VDIM / 16) * 8 * 64 / 256, 256, 0, stream>>>(cb, cbf);
    hipMemsetAsync(cnt, 0, NPIX * sizeof(int), stream);
    screen<<<256, 512, 0, stream>>>(zbf, cbf, C32, thr, cnt, cand);
    rerank<<<NPIX / 4, 256, 0, stream>>>(z32, cb, A32, C32, cand, cnt, tok_i, tok_f);
    post_quant<<<NPIX / 32, 256, 0, stream>>>(cb, Wpost, bpost, tok_i, rec);
}